// Round 6
// baseline (474.782 us; speedup 1.0000x reference)
//
#include <hip/hip_runtime.h>
#include <math.h>

#define S_LEN 1024
#define HID_DIM 4096
#define NH 32
#define NKV 8
#define DH 128

typedef __attribute__((ext_vector_type(8))) short sh8;
typedef __attribute__((ext_vector_type(4))) short sh4;
typedef __attribute__((ext_vector_type(4))) float f4;

__device__ __forceinline__ unsigned short f2bf(float x) {
    union { float f; unsigned int u; } v; v.f = x;
    unsigned int r = v.u + 0x7FFFu + ((v.u >> 16) & 1u);
    return (unsigned short)(r >> 16);
}

__device__ __forceinline__ void gl_lds16(const unsigned short* g, unsigned short* l) {
    __builtin_amdgcn_global_load_lds(
        (const __attribute__((address_space(1))) unsigned int*)g,
        (__attribute__((address_space(3))) unsigned int*)l, 16, 0, 0);
}

// ============================ FAST PATH =====================================

__global__ void cvt_hw(const float* __restrict__ hidden, const float* __restrict__ Wq,
                       const float* __restrict__ Wk, const float* __restrict__ Wv,
                       unsigned short* __restrict__ hbf, unsigned short* __restrict__ wbuf)
{
    const int idx = blockIdx.x * 256 + threadIdx.x;
    const int NH4 = (S_LEN * HID_DIM) / 4;
    float4 v;
    sh4* dst;
    if (idx < NH4) {
        v = ((const float4*)hidden)[idx];
        dst = (sh4*)hbf + idx;
    } else {
        const int j = idx - NH4;
        const int row = j >> 10;
        if (row < 4096)      v = ((const float4*)Wq)[j];
        else if (row < 5120) v = ((const float4*)Wk)[j - 4096 * 1024];
        else                 v = ((const float4*)Wv)[j - 5120 * 1024];
        dst = (sh4*)wbuf + j;
    }
    sh4 o;
    o.x = (short)f2bf(v.x); o.y = (short)f2bf(v.y);
    o.z = (short)f2bf(v.z); o.w = (short)f2bf(v.w);
    *dst = o;
}

__global__ void cvt_wo(const float* __restrict__ Wo, unsigned short* __restrict__ wbuf)
{
    const int idx = blockIdx.x * 256 + threadIdx.x;
    const float4 v = ((const float4*)Wo)[idx];
    sh4 o;
    o.x = (short)f2bf(v.x); o.y = (short)f2bf(v.y);
    o.z = (short)f2bf(v.z); o.w = (short)f2bf(v.w);
    ((sh4*)wbuf)[idx] = o;
}

// bf16 GEMM v3: 128x128 tile, BK=32 (16KB LDS, low VGPR -> max resident
// blocks), pair-interleaved 3-bit XOR swizzle (two 64B rows = one 128B pair;
// 16B chunk s of pair p stored at s^(p&7)) -> conflict-free b128 reads with
// glds-compatible contiguous staging. Split-K + fp32 atomicAdd epilogue.
__global__ __launch_bounds__(256)
void gemm32s(const unsigned short* __restrict__ A, const unsigned short* __restrict__ B,
             float* __restrict__ C, int K, int kslices, int ldc)
{
    __shared__ __attribute__((aligned(16))) unsigned short sA[128 * 32];
    __shared__ __attribute__((aligned(16))) unsigned short sB[128 * 32];

    const int tid  = threadIdx.x;
    const int wave = tid >> 6;
    const int lane = tid & 63;
    const int l15  = lane & 15;
    const int quad = lane >> 4;
    const int m0   = blockIdx.y * 128;
    const int n0   = blockIdx.x * 128;
    const int wm   = (wave >> 1) * 64;
    const int wn   = (wave & 1) * 64;

    const int kchunk = K / kslices;
    const int kbeg = blockIdx.z * kchunk;
    const int kend = kbeg + kchunk;

    // staging (2 glds per matrix per wave, 16 rows = 8 pairs each):
    // lane l -> pair l>>3, phys slot l&7; logical slot s = (l&7)^((l>>3)&7)
    // -> source row 2*(l>>3)+(s>>2), source chunk s&3.
    const int sslot = (lane & 7) ^ ((lane >> 3) & 7);
    const int srow  = 2 * (lane >> 3) + (sslot >> 2);
    const int scol  = (sslot & 3) * 8;
    const unsigned short* Ag = A + (size_t)(m0 + wave * 32 + srow) * K + scol;
    const unsigned short* Bg = B + (size_t)(n0 + wave * 32 + srow) * K + scol;
    unsigned short* sAw = &sA[wave * 32 * 32];
    unsigned short* sBw = &sB[wave * 32 * 32];

    f4 acc[4][4];
#pragma unroll
    for (int i = 0; i < 4; i++)
#pragma unroll
        for (int j = 0; j < 4; j++)
            acc[i][j] = f4{0.0f, 0.0f, 0.0f, 0.0f};

    // read-side: row = base + l15, logical chunk = quad ->
    // shorts index = (row>>1)*64 + (((row&1)*4 + quad) ^ (l15>>1)) * 8
    const int rphys = ((((l15 & 1) << 2) + quad) ^ (l15 >> 1)) * 8;

    for (int k0 = kbeg; k0 < kend; k0 += 32) {
        __syncthreads();
        gl_lds16(Ag + k0,          sAw);
        gl_lds16(Ag + 16 * K + k0, sAw + 16 * 32);
        gl_lds16(Bg + k0,          sBw);
        gl_lds16(Bg + 16 * K + k0, sBw + 16 * 32);
        __syncthreads();

        sh8 af[4], bf[4];
#pragma unroll
        for (int i = 0; i < 4; i++)
            af[i] = *(const sh8*)(&sA[((wm + i * 16 + l15) >> 1) * 64 + rphys]);
#pragma unroll
        for (int j = 0; j < 4; j++)
            bf[j] = *(const sh8*)(&sB[((wn + j * 16 + l15) >> 1) * 64 + rphys]);
#pragma unroll
        for (int i = 0; i < 4; i++)
#pragma unroll
            for (int j = 0; j < 4; j++)
                acc[i][j] = __builtin_amdgcn_mfma_f32_16x16x32_bf16(af[i], bf[j], acc[i][j], 0, 0, 0);
    }

#pragma unroll
    for (int i = 0; i < 4; i++) {
        const int mrow = m0 + wm + i * 16 + quad * 4;
#pragma unroll
        for (int j = 0; j < 4; j++) {
            const int ncol = n0 + wn + j * 16 + l15;
            if (kslices == 1) {
#pragma unroll
                for (int r = 0; r < 4; r++)
                    C[(size_t)(mrow + r) * ldc + ncol] = acc[i][j][r];
            } else {
#pragma unroll
                for (int r = 0; r < 4; r++)
                    atomicAdd(&C[(size_t)(mrow + r) * ldc + ncol], acc[i][j][r]);
            }
        }
    }
}

__global__ void prep2(const float* __restrict__ qkv, const int* __restrict__ pos_ids,
                      const float* __restrict__ prior,
                      unsigned short* __restrict__ Qb, unsigned short* __restrict__ Kb,
                      unsigned short* __restrict__ Vt, float* __restrict__ addvT)
{
    const int idx = blockIdx.x * blockDim.x + threadIdx.x;
    const int NQ = S_LEN * 40 * 64;
    const int NV = S_LEN * NKV * DH;
    if (idx < NQ) {
        const int s   = idx / (40 * 64);
        const int rem = idx % (40 * 64);
        const int hh  = rem >> 6;
        const int i   = rem & 63;
        const float pos  = (float)pos_ids[s];
        const float invf = exp2f(-13.287712379549449f * (i * 0.015625f));
        const float ph = pos * invf;
        const float c = cosf(ph), sn = sinf(ph);
        if (hh < NH) {
            const float* base = qkv + (size_t)s * 6144 + hh * 128;
            const float x1 = base[i], x2 = base[i + 64];
            const float sc = 0.08838834764831845f * 1.4426950408889634f; // log2e/sqrt(128)
            unsigned short* q = Qb + ((size_t)hh * S_LEN + s) * DH;
            q[i]      = f2bf((x1 * c - x2 * sn) * sc);
            q[i + 64] = f2bf((x2 * c + x1 * sn) * sc);
        } else {
            const int kvh = hh - NH;
            const float* base = qkv + (size_t)s * 6144 + 4096 + kvh * 128;
            const float p = prior[s];
            const float gamma = fminf(fmaxf(1.0f + 0.5f * p, 0.5f), 2.0f);
            const float x1 = base[i], x2 = base[i + 64];
            unsigned short* kp = Kb + ((size_t)kvh * S_LEN + s) * DH;
            kp[i]      = f2bf((x1 * c - x2 * sn) * gamma);
            kp[i + 64] = f2bf((x2 * c + x1 * sn) * gamma);
        }
    } else if (idx < NQ + NV) {
        const int j = idx - NQ;
        const int s   = j / (NKV * DH);
        const int rem = j % (NKV * DH);
        const int kvh = rem >> 7;
        const int d   = rem & 127;
        const float p = prior[s];
        const float eta = fminf(fmaxf(1.0f + 0.5f * p, 0.5f), 2.0f);
        const float val = qkv[(size_t)s * 6144 + 5120 + kvh * 128 + d] * eta;
        Vt[((size_t)kvh * DH + d) * S_LEN + s] = f2bf(val);
    } else {
        const int j2 = idx - NQ - NV;
        if (j2 < 4 * S_LEN) {
            const int c = j2 >> 10;
            const int s = j2 & 1023;
            const float p = prior[s];
            const float bias = fminf(fmaxf(p, -5.0f), 5.0f);
            float v = 0.0f;
            if (c & 1) v += bias;
            if (c & 2) v += log1pf(0.5f * p);
            addvT[j2] = v * 1.4426950408889634f;
        }
    }
}

// Flash GQA attention v5: block-cooperative glds staging of K/V chunks,
// XOR-swizzled sK/sV, fixed-max exp2 softmax, waves own q-rows.
__global__ __launch_bounds__(256)
void attn5(const unsigned short* __restrict__ Qb, const unsigned short* __restrict__ Kb,
           const unsigned short* __restrict__ Vt, const float* __restrict__ addvT,
           const float* __restrict__ hm1, const float* __restrict__ hm2,
           unsigned short* __restrict__ ctx)
{
    __shared__ __attribute__((aligned(16))) unsigned short sK[32 * 128]; // [key][d] swz r&7
    __shared__ __attribute__((aligned(16))) unsigned short sV[128 * 32]; // [d][key] swz r&3
    __shared__ __attribute__((aligned(16))) short sP[4][16 * 40];

    const int h    = blockIdx.x;
    const int qb   = blockIdx.y;
    const int tid  = threadIdx.x;
    const int wave = tid >> 6;
    const int lane = tid & 63;
    const int l15  = lane & 15;
    const int quad = lane >> 4;
    const int q0   = qb * 64 + wave * 16;
    const int kvh  = h >> 2;
    const int combo = (hm1[h] > 0.5f ? 1 : 0) + (hm2[h] > 0.5f ? 2 : 0);
    const float* av = addvT + combo * S_LEN;

    const unsigned short* ksrcE = Kb + ((size_t)kvh * S_LEN + (lane >> 4)) * DH
                                  + (((lane & 15) ^ (lane >> 4)) * 8);
    const unsigned short* ksrcO = Kb + ((size_t)kvh * S_LEN + (lane >> 4)) * DH
                                  + (((lane & 15) ^ (4 + (lane >> 4))) * 8);
    const unsigned short* vsrc0 = Vt + ((size_t)kvh * DH + (lane >> 2)) * S_LEN
                                  + (((lane & 3) ^ ((lane >> 2) & 3)) * 8);

    sh8 qf[4];
    {
        const unsigned short* qbase = Qb + ((size_t)h * S_LEN + q0 + l15) * DH + quad * 8;
#pragma unroll
        for (int kc = 0; kc < 4; kc++)
            qf[kc] = *(const sh8*)(qbase + kc * 32);
    }

    f4 O[8];
#pragma unroll
    for (int dt = 0; dt < 8; dt++) O[dt] = f4{0.0f, 0.0f, 0.0f, 0.0f};
    float lrun[4] = {0.0f, 0.0f, 0.0f, 0.0f};

    short* pl = &sP[wave][0];
    const int sw = l15 & 7;
    const int sv = l15 & 3;
    const int nch = 2 * qb + 2;

    for (int c = 0; c < nch; c++) {
        const int k0 = c * 32;
        __syncthreads();
        if (wave < 2) {
#pragma unroll
            for (int j = 0; j < 4; j++) {
                const int i = wave * 4 + j;
                const unsigned short* src = (j & 1) ? ksrcO : ksrcE;
                gl_lds16(src + (size_t)(k0 + 4 * i) * DH, &sK[i * 512]);
            }
        } else {
#pragma unroll
            for (int j = 0; j < 4; j++) {
                const int i = (wave - 2) * 4 + j;
                gl_lds16(vsrc0 + (size_t)(16 * i) * S_LEN + k0, &sV[i * 512]);
            }
        }
        __syncthreads();

#pragma unroll
        for (int t = 0; t < 2; t++) {
            f4 a = f4{0.0f, 0.0f, 0.0f, 0.0f};
#pragma unroll
            for (int kc = 0; kc < 4; kc++) {
                const sh8 kfr = *(const sh8*)(&sK[(t * 16 + l15) * 128 + ((kc * 4 + quad) ^ sw) * 8]);
                a = __builtin_amdgcn_mfma_f32_16x16x32_bf16(qf[kc], kfr, a, 0, 0, 0);
            }
            const int key = k0 + t * 16 + l15;
            const float ad = av[key];
#pragma unroll
            for (int r = 0; r < 4; r++) {
                const int qrow = q0 + quad * 4 + r;
                float ex = exp2f(a[r] + ad);
                ex = (key <= qrow) ? ex : 0.0f;
                lrun[r] += ex;
                pl[(quad * 4 + r) * 40 + t * 16 + l15] = (short)f2bf(ex);
            }
        }
        asm volatile("s_waitcnt lgkmcnt(0)" ::: "memory");
        const sh8 ap = *(const sh8*)(&pl[l15 * 40 + quad * 8]);
#pragma unroll
        for (int dt = 0; dt < 8; dt++) {
            const sh8 vfr = *(const sh8*)(&sV[(dt * 16 + l15) * 32 + (quad ^ sv) * 8]);
            O[dt] = __builtin_amdgcn_mfma_f32_16x16x32_bf16(ap, vfr, O[dt], 0, 0, 0);
        }
    }

#pragma unroll
    for (int r = 0; r < 4; r++) {
        float l = lrun[r];
        l += __shfl_xor(l, 1); l += __shfl_xor(l, 2);
        l += __shfl_xor(l, 4); l += __shfl_xor(l, 8);
        const float inv = 1.0f / l;
        const int row = q0 + quad * 4 + r;
        unsigned short* cp = ctx + (size_t)row * HID_DIM + h * DH;
#pragma unroll
        for (int dt = 0; dt < 8; dt++)
            cp[dt * 16 + l15] = f2bf(O[dt][r] * inv);
    }
}

// ========================= FALLBACK (round-1, proven @54.5MB) ===============

#define LDSW 40

__global__ __launch_bounds__(256)
void gemm_bt(const float* __restrict__ A,
             const float* __restrict__ B0, const float* __restrict__ B1,
             const float* __restrict__ B2, int n_b1, int n_b2,
             float* __restrict__ C, int M, int N, int K, int ldc)
{
    __shared__ __attribute__((aligned(16))) short sA[128 * LDSW];
    __shared__ __attribute__((aligned(16))) short sB[128 * LDSW];
    const int tid  = threadIdx.x;
    const int m0   = blockIdx.y * 128;
    const int n0   = blockIdx.x * 128;
    const float* Bp = B0; int nloc = n0;
    if (n0 >= n_b2)      { Bp = B2; nloc = n0 - n_b2; }
    else if (n0 >= n_b1) { Bp = B1; nloc = n0 - n_b1; }
    const int wave = tid >> 6, lane = tid & 63;
    const int l15 = lane & 15, quad = lane >> 4;
    const int wm = (wave >> 1) * 64, wn = (wave & 1) * 64;
    const int rb = tid >> 3, c4 = (tid & 7) * 4;
    f4 acc[4][4];
#pragma unroll
    for (int i = 0; i < 4; i++)
#pragma unroll
        for (int j = 0; j < 4; j++) acc[i][j] = f4{0.0f, 0.0f, 0.0f, 0.0f};
    for (int k0 = 0; k0 < K; k0 += 32) {
        __syncthreads();
#pragma unroll
        for (int i = 0; i < 4; i++) {
            const int row = rb + 32 * i;
            const float4 va = *(const float4*)(A  + (size_t)(m0 + row) * K + k0 + c4);
            const float4 vb = *(const float4*)(Bp + (size_t)(nloc + row) * K + k0 + c4);
            sh4 sa, sb;
            sa.x = (short)f2bf(va.x); sa.y = (short)f2bf(va.y);
            sa.z = (short)f2bf(va.z); sa.w = (short)f2bf(va.w);
            sb.x = (short)f2bf(vb.x); sb.y = (short)f2bf(vb.y);
            sb.z = (short)f2bf(vb.z); sb.w = (short)f2bf(vb.w);
            *(sh4*)(&sA[row * LDSW + c4]) = sa;
            *(sh4*)(&sB[row * LDSW + c4]) = sb;
        }
        __syncthreads();
        sh8 af[4], bf[4];
#pragma unroll
        for (int i = 0; i < 4; i++) af[i] = *(const sh8*)(&sA[(wm + i * 16 + l15) * LDSW + quad * 8]);
#pragma unroll
        for (int j = 0; j < 4; j++) bf[j] = *(const sh8*)(&sB[(wn + j * 16 + l15) * LDSW + quad * 8]);
#pragma unroll
        for (int i = 0; i < 4; i++)
#pragma unroll
            for (int j = 0; j < 4; j++)
                acc[i][j] = __builtin_amdgcn_mfma_f32_16x16x32_bf16(af[i], bf[j], acc[i][j], 0, 0, 0);
    }
#pragma unroll
    for (int i = 0; i < 4; i++) {
        const int mrow = m0 + wm + i * 16 + quad * 4;
#pragma unroll
        for (int j = 0; j < 4; j++) {
            const int ncol = n0 + wn + j * 16 + l15;
#pragma unroll
            for (int r = 0; r < 4; r++)
                C[(size_t)(mrow + r) * ldc + ncol] = acc[i][j][r];
        }
    }
}

__global__ void prep_rope(const float* __restrict__ qkv, const int* __restrict__ pos_ids,
                          const float* __restrict__ prior,
                          unsigned short* __restrict__ Qb, unsigned short* __restrict__ Kb,
                          unsigned short* __restrict__ Vt)
{
    const int idx = blockIdx.x * blockDim.x + threadIdx.x;
    const int NQ = S_LEN * 40 * 64;
    if (idx < NQ) {
        const int s = idx / (40 * 64);
        const int rem = idx % (40 * 64);
        const int hh = rem >> 6, i = rem & 63;
        const float pos = (float)pos_ids[s];
        const float invf = exp2f(-13.287712379549449f * (i * 0.015625f));
        const float ph = pos * invf;
        const float c = cosf(ph), sn = sinf(ph);
        if (hh < NH) {
            const float* base = qkv + (size_t)s * 6144 + hh * 128;
            const float x1 = base[i], x2 = base[i + 64];
            const float sc = 0.08838834764831845f;
            unsigned short* q = Qb + ((size_t)hh * S_LEN + s) * DH;
            q[i] = f2bf((x1 * c - x2 * sn) * sc);
            q[i + 64] = f2bf((x2 * c + x1 * sn) * sc);
        } else {
            const int kvh = hh - NH;
            const float* base = qkv + (size_t)s * 6144 + 4096 + kvh * 128;
            const float p = prior[s];
            const float gamma = fminf(fmaxf(1.0f + 0.5f * p, 0.5f), 2.0f);
            const float x1 = base[i], x2 = base[i + 64];
            unsigned short* kp = Kb + ((size_t)kvh * S_LEN + s) * DH;
            kp[i] = f2bf((x1 * c - x2 * sn) * gamma);
            kp[i + 64] = f2bf((x2 * c + x1 * sn) * gamma);
        }
    } else {
        const int j = idx - NQ;
        if (j < S_LEN * NKV * DH) {
            const int s = j / (NKV * DH);
            const int rem = j % (NKV * DH);
            const int kvh = rem >> 7, d = rem & 127;
            const float p = prior[s];
            const float eta = fminf(fmaxf(1.0f + 0.5f * p, 0.5f), 2.0f);
            const float val = qkv[(size_t)s * 6144 + 5120 + kvh * 128 + d] * eta;
            Vt[((size_t)kvh * DH + d) * S_LEN + s] = f2bf(val);
        }
    }
}

__global__ __launch_bounds__(256)
void attn_kernel(const unsigned short* __restrict__ Qb, const unsigned short* __restrict__ Kb,
                 const unsigned short* __restrict__ Vt, const float* __restrict__ prior,
                 const float* __restrict__ hm1, const float* __restrict__ hm2,
                 float* __restrict__ ctx)
{
    __shared__ __attribute__((aligned(16))) short p_lds[4][16 * LDSW];
    const int h = blockIdx.x, qb = blockIdx.y;
    const int wave = threadIdx.x >> 6, lane = threadIdx.x & 63;
    const int l15 = lane & 15, quad = lane >> 4;
    const int q0 = qb * 64 + wave * 16;
    const int kvh = h >> 2;
    const float m1 = hm1[h], m2 = hm2[h];
    const float NEG = -3.0e38f;
    sh8 qf[4];
    {
        const unsigned short* qbase = Qb + ((size_t)h * S_LEN + q0 + l15) * DH + quad * 8;
#pragma unroll
        for (int kc = 0; kc < 4; kc++) qf[kc] = *(const sh8*)(qbase + kc * 32);
    }
    f4 O[8];
#pragma unroll
    for (int dt = 0; dt < 8; dt++) O[dt] = f4{0.0f, 0.0f, 0.0f, 0.0f};
    float mrun[4], lrun[4];
#pragma unroll
    for (int r = 0; r < 4; r++) { mrun[r] = NEG; lrun[r] = 0.0f; }
    short* pl = &p_lds[wave][0];
    const int qmax = q0 + 15;
    for (int key0 = 0; key0 <= qmax; key0 += 32) {
        float sc[2][4];
#pragma unroll
        for (int t = 0; t < 2; t++) {
            const int kt = key0 + t * 16;
            const unsigned short* kb = Kb + ((size_t)kvh * S_LEN + kt + l15) * DH + quad * 8;
            f4 a = f4{0.0f, 0.0f, 0.0f, 0.0f};
#pragma unroll
            for (int kc = 0; kc < 4; kc++) {
                const sh8 bfr = *(const sh8*)(kb + kc * 32);
                a = __builtin_amdgcn_mfma_f32_16x16x32_bf16(qf[kc], bfr, a, 0, 0, 0);
            }
            const int key = kt + l15;
            const float p = prior[key];
            const float bias = fminf(fmaxf(p, -5.0f), 5.0f);
            const float addv = m1 * bias + m2 * logf(1.0f + 0.5f * p);
#pragma unroll
            for (int r = 0; r < 4; r++) {
                const int qrow = q0 + quad * 4 + r;
                sc[t][r] = (key <= qrow) ? (a[r] + addv) : NEG;
            }
        }
        float cm[4], mnew[4], alpha[4], rs[4];
#pragma unroll
        for (int r = 0; r < 4; r++) {
            cm[r] = fmaxf(sc[0][r], sc[1][r]);
            cm[r] = fmaxf(cm[r], __shfl_xor(cm[r], 1));
            cm[r] = fmaxf(cm[r], __shfl_xor(cm[r], 2));
            cm[r] = fmaxf(cm[r], __shfl_xor(cm[r], 4));
            cm[r] = fmaxf(cm[r], __shfl_xor(cm[r], 8));
            mnew[r] = fmaxf(mrun[r], cm[r]);
            alpha[r] = expf(mrun[r] - mnew[r]);
        }
        float e[2][4];
#pragma unroll
        for (int t = 0; t < 2; t++)
#pragma unroll
            for (int r = 0; r < 4; r++) e[t][r] = expf(sc[t][r] - mnew[r]);
#pragma unroll
        for (int r = 0; r < 4; r++) {
            rs[r] = e[0][r] + e[1][r];
            rs[r] += __shfl_xor(rs[r], 1); rs[r] += __shfl_xor(rs[r], 2);
            rs[r] += __shfl_xor(rs[r], 4); rs[r] += __shfl_xor(rs[r], 8);
            lrun[r] = lrun[r] * alpha[r] + rs[r];
            mrun[r] = mnew[r];
        }
#pragma unroll
        for (int dt = 0; dt < 8; dt++)
#pragma unroll
            for (int r = 0; r < 4; r++) O[dt][r] *= alpha[r];
#pragma unroll
        for (int t = 0; t < 2; t++)
#pragma unroll
            for (int r = 0; r < 4; r++)
                pl[(quad * 4 + r) * LDSW + t * 16 + l15] = (short)f2bf(e[t][r]);
        asm volatile("s_waitcnt lgkmcnt(0)" ::: "memory");
        const sh8 ap = *(const sh8*)(&pl[l15 * LDSW + quad * 8]);
        const unsigned short* vb = Vt + ((size_t)kvh * DH + l15) * S_LEN + key0 + quad * 8;
#pragma unroll
        for (int dt = 0; dt < 8; dt++) {
            const sh8 bfv = *(const sh8*)(vb + (size_t)dt * 16 * S_LEN);
            O[dt] = __builtin_amdgcn_mfma_f32_16x16x32_bf16(ap, bfv, O[dt], 0, 0, 0);
        }
    }
#pragma unroll
    for (int r = 0; r < 4; r++) {
        const float inv = 1.0f / lrun[r];
        const int row = q0 + quad * 4 + r;
        float* cp = ctx + (size_t)row * HID_DIM + h * DH;
#pragma unroll
        for (int dt = 0; dt < 8; dt++) cp[dt * 16 + l15] = O[dt][r] * inv;
    }
}

// ============================================================================

extern "C" void kernel_launch(void* const* d_in, const int* in_sizes, int n_in,
                              void* d_out, int out_size, void* d_ws, size_t ws_size,
                              hipStream_t stream)
{
    const float* hidden  = (const float*)d_in[0];
    const int*   pos_ids = (const int*)d_in[2];
    const float* Wq = (const float*)d_in[3];
    const float* Wk = (const float*)d_in[4];
    const float* Wv = (const float*)d_in[5];
    const float* Wo = (const float*)d_in[6];
    const float* prior = (const float*)d_in[7];
    const float* hm1 = (const float*)d_in[8];
    const float* hm2 = (const float*)d_in[9];
    float* out = (float*)d_out;
    char* ws = (char*)d_ws;

    const size_t FAST_NEED = 96485376ull;
    if (ws_size >= FAST_NEED) {
        unsigned short* Wbuf = (unsigned short*)ws;                  // 50,331,648
        unsigned short* Cbf  = (unsigned short*)(ws + 33554432);     // ctx bf16, aliases Wbuf tail in phase 2
        unsigned short* Hbf  = (unsigned short*)(ws + 50331648);     //  8,388,608
        float*          qkv  = (float*)(ws + 58720256);              // 25,165,824
        unsigned short* Qb   = (unsigned short*)(ws + 83886080);     //  8,388,608
        unsigned short* Kb   = (unsigned short*)(ws + 92274688);     //  2,097,152
        unsigned short* Vt   = (unsigned short*)(ws + 94371840);     //  2,097,152
        float*          addv = (float*)(ws + 96468992);              //     16,384

        hipMemsetAsync(qkv, 0, 25165824, stream);
        hipMemsetAsync(out, 0, 16777216, stream);
        cvt_hw<<<28672, 256, 0, stream>>>(hidden, Wq, Wk, Wv, Hbf, Wbuf);
        gemm32s<<<dim3(48, 8, 4), 256, 0, stream>>>(Hbf, Wbuf, qkv, 4096, 4, 6144);
        prep2<<<14352, 256, 0, stream>>>(qkv, pos_ids, prior, Qb, Kb, Vt, addv);
        cvt_wo<<<16384, 256, 0, stream>>>(Wo, Wbuf);                 // reuse Wbuf[0:33.5MB]
        attn5<<<dim3(32, 16), 256, 0, stream>>>(Qb, Kb, Vt, addv, hm1, hm2, Cbf);
        gemm32s<<<dim3(32, 8, 4), 256, 0, stream>>>(Cbf, Wbuf, out, 4096, 4, 4096);
    } else {
        float*          qkv = (float*)ws;
        float*          ctx = (float*)(ws + 25165824);
        unsigned short* Qb  = (unsigned short*)(ws + 41943040);
        unsigned short* Kb  = (unsigned short*)(ws + 50331648);
        unsigned short* Vt  = (unsigned short*)(ws + 52428800);
        gemm_bt<<<dim3(48, 8), 256, 0, stream>>>(hidden, Wq, Wk, Wv, 4096, 5120,
                                                 qkv, 1024, 6144, 4096, 6144);
        prep_rope<<<14336, 256, 0, stream>>>(qkv, pos_ids, prior, Qb, Kb, Vt);
        attn_kernel<<<dim3(32, 16), 256, 0, stream>>>(Qb, Kb, Vt, prior, hm1, hm2, ctx);
        gemm_bt<<<dim3(32, 8), 256, 0, stream>>>(ctx, Wo, Wo, Wo, 1 << 30, 1 << 30,
                                                 out, 1024, 4096, 4096, 4096);
    }
}

// Round 7
// 430.700 us; speedup vs baseline: 1.1024x; 1.1024x over previous
//
#include <hip/hip_runtime.h>
#include <math.h>

#define S_LEN 1024
#define HID_DIM 4096
#define NH 32
#define NKV 8
#define DH 128

typedef __attribute__((ext_vector_type(8))) short sh8;
typedef __attribute__((ext_vector_type(4))) short sh4;
typedef __attribute__((ext_vector_type(4))) float f4;

__device__ __forceinline__ unsigned short f2bf(float x) {
    union { float f; unsigned int u; } v; v.f = x;
    unsigned int r = v.u + 0x7FFFu + ((v.u >> 16) & 1u);
    return (unsigned short)(r >> 16);
}

__device__ __forceinline__ void gl_lds16(const unsigned short* g, unsigned short* l) {
    __builtin_amdgcn_global_load_lds(
        (const __attribute__((address_space(1))) unsigned int*)g,
        (__attribute__((address_space(3))) unsigned int*)l, 16, 0, 0);
}

// ============================ FAST PATH =====================================

__global__ void cvt_hw(const float* __restrict__ hidden, const float* __restrict__ Wq,
                       const float* __restrict__ Wk, const float* __restrict__ Wv,
                       unsigned short* __restrict__ hbf, unsigned short* __restrict__ wbuf)
{
    const int idx = blockIdx.x * 256 + threadIdx.x;
    const int NH4 = (S_LEN * HID_DIM) / 4;
    float4 v;
    sh4* dst;
    if (idx < NH4) {
        v = ((const float4*)hidden)[idx];
        dst = (sh4*)hbf + idx;
    } else {
        const int j = idx - NH4;
        const int row = j >> 10;
        if (row < 4096)      v = ((const float4*)Wq)[j];
        else if (row < 5120) v = ((const float4*)Wk)[j - 4096 * 1024];
        else                 v = ((const float4*)Wv)[j - 5120 * 1024];
        dst = (sh4*)wbuf + j;
    }
    sh4 o;
    o.x = (short)f2bf(v.x); o.y = (short)f2bf(v.y);
    o.z = (short)f2bf(v.z); o.w = (short)f2bf(v.w);
    *dst = o;
}

__global__ void cvt_wo(const float* __restrict__ Wo, unsigned short* __restrict__ wbuf)
{
    const int idx = blockIdx.x * 256 + threadIdx.x;
    const float4 v = ((const float4*)Wo)[idx];
    sh4 o;
    o.x = (short)f2bf(v.x); o.y = (short)f2bf(v.y);
    o.z = (short)f2bf(v.z); o.w = (short)f2bf(v.w);
    ((sh4*)wbuf)[idx] = o;
}

// bf16 GEMM v4: 128x128 tile, BK=32, pair-interleaved XOR swizzle (0 bank
// conflicts, r6-verified), DOUBLE-BUFFERED LDS with ONE barrier per K-iter:
// glds for tile k+1 issued before computing tile k, so the compiler's
// vmcnt(0)-before-barrier drain overlaps the MFMA phase instead of exposing
// full memory latency. Split-K + fp32 atomicAdd epilogue.
__global__ __launch_bounds__(256)
void gemm_db(const unsigned short* __restrict__ A, const unsigned short* __restrict__ B,
             float* __restrict__ C, int K, int kslices, int ldc)
{
    __shared__ __attribute__((aligned(16))) unsigned short sA[2][128 * 32];
    __shared__ __attribute__((aligned(16))) unsigned short sB[2][128 * 32];

    const int tid  = threadIdx.x;
    const int wave = tid >> 6;
    const int lane = tid & 63;
    const int l15  = lane & 15;
    const int quad = lane >> 4;
    const int m0   = blockIdx.y * 128;
    const int n0   = blockIdx.x * 128;
    const int wm   = (wave >> 1) * 64;
    const int wn   = (wave & 1) * 64;

    const int kchunk = K / kslices;
    const int kbeg = blockIdx.z * kchunk;
    const int kend = kbeg + kchunk;

    // staging: lane l -> pair l>>3, phys slot l&7; logical slot
    // s=(l&7)^((l>>3)&7) -> src row 2*(l>>3)+(s>>2), src 16B-chunk s&3.
    const int sslot = (lane & 7) ^ ((lane >> 3) & 7);
    const int srow  = 2 * (lane >> 3) + (sslot >> 2);
    const int scol  = (sslot & 3) * 8;
    const unsigned short* Ag = A + (size_t)(m0 + wave * 32 + srow) * K + scol;
    const unsigned short* Bg = B + (size_t)(n0 + wave * 32 + srow) * K + scol;

    f4 acc[4][4];
#pragma unroll
    for (int i = 0; i < 4; i++)
#pragma unroll
        for (int j = 0; j < 4; j++)
            acc[i][j] = f4{0.0f, 0.0f, 0.0f, 0.0f};

    // read-side: row base + l15, logical chunk quad ->
    // shorts index (row>>1)*64 + ((((row&1)<<2)+quad) ^ (l15>>1)) * 8
    const int rphys = ((((l15 & 1) << 2) + quad) ^ (l15 >> 1)) * 8;

    // prologue: stage buffer 0
    {
        unsigned short* sAw = &sA[0][wave * 1024];
        unsigned short* sBw = &sB[0][wave * 1024];
        gl_lds16(Ag + kbeg,          sAw);
        gl_lds16(Ag + 16 * K + kbeg, sAw + 512);
        gl_lds16(Bg + kbeg,          sBw);
        gl_lds16(Bg + 16 * K + kbeg, sBw + 512);
    }

    for (int k0 = kbeg; k0 < kend; k0 += 32) {
        const int cur = ((k0 - kbeg) >> 5) & 1;
        __syncthreads();                       // staging of 'cur' complete
        const int k1 = k0 + 32;
        if (k1 < kend) {                       // prefetch next tile into cur^1
            unsigned short* sAw = &sA[cur ^ 1][wave * 1024];
            unsigned short* sBw = &sB[cur ^ 1][wave * 1024];
            gl_lds16(Ag + k1,          sAw);
            gl_lds16(Ag + 16 * K + k1, sAw + 512);
            gl_lds16(Bg + k1,          sBw);
            gl_lds16(Bg + 16 * K + k1, sBw + 512);
        }

        sh8 af[4], bf[4];
#pragma unroll
        for (int i = 0; i < 4; i++)
            af[i] = *(const sh8*)(&sA[cur][((wm + i * 16 + l15) >> 1) * 64 + rphys]);
#pragma unroll
        for (int j = 0; j < 4; j++)
            bf[j] = *(const sh8*)(&sB[cur][((wn + j * 16 + l15) >> 1) * 64 + rphys]);
#pragma unroll
        for (int i = 0; i < 4; i++)
#pragma unroll
            for (int j = 0; j < 4; j++)
                acc[i][j] = __builtin_amdgcn_mfma_f32_16x16x32_bf16(af[i], bf[j], acc[i][j], 0, 0, 0);
    }

#pragma unroll
    for (int i = 0; i < 4; i++) {
        const int mrow = m0 + wm + i * 16 + quad * 4;
#pragma unroll
        for (int j = 0; j < 4; j++) {
            const int ncol = n0 + wn + j * 16 + l15;
            if (kslices == 1) {
#pragma unroll
                for (int r = 0; r < 4; r++)
                    C[(size_t)(mrow + r) * ldc + ncol] = acc[i][j][r];
            } else {
#pragma unroll
                for (int r = 0; r < 4; r++)
                    atomicAdd(&C[(size_t)(mrow + r) * ldc + ncol], acc[i][j][r]);
            }
        }
    }
}

__global__ void prep2(const float* __restrict__ qkv, const int* __restrict__ pos_ids,
                      const float* __restrict__ prior,
                      unsigned short* __restrict__ Qb, unsigned short* __restrict__ Kb,
                      unsigned short* __restrict__ Vt, float* __restrict__ addvT)
{
    const int idx = blockIdx.x * blockDim.x + threadIdx.x;
    const int NQ = S_LEN * 40 * 64;
    const int NV = S_LEN * NKV * DH;
    if (idx < NQ) {
        const int s   = idx / (40 * 64);
        const int rem = idx % (40 * 64);
        const int hh  = rem >> 6;
        const int i   = rem & 63;
        const float pos  = (float)pos_ids[s];
        const float invf = exp2f(-13.287712379549449f * (i * 0.015625f));
        const float ph = pos * invf;
        const float c = cosf(ph), sn = sinf(ph);
        if (hh < NH) {
            const float* base = qkv + (size_t)s * 6144 + hh * 128;
            const float x1 = base[i], x2 = base[i + 64];
            const float sc = 0.08838834764831845f * 1.4426950408889634f; // log2e/sqrt(128)
            unsigned short* q = Qb + ((size_t)hh * S_LEN + s) * DH;
            q[i]      = f2bf((x1 * c - x2 * sn) * sc);
            q[i + 64] = f2bf((x2 * c + x1 * sn) * sc);
        } else {
            const int kvh = hh - NH;
            const float* base = qkv + (size_t)s * 6144 + 4096 + kvh * 128;
            const float p = prior[s];
            const float gamma = fminf(fmaxf(1.0f + 0.5f * p, 0.5f), 2.0f);
            const float x1 = base[i], x2 = base[i + 64];
            unsigned short* kp = Kb + ((size_t)kvh * S_LEN + s) * DH;
            kp[i]      = f2bf((x1 * c - x2 * sn) * gamma);
            kp[i + 64] = f2bf((x2 * c + x1 * sn) * gamma);
        }
    } else if (idx < NQ + NV) {
        const int j = idx - NQ;
        const int s   = j / (NKV * DH);
        const int rem = j % (NKV * DH);
        const int kvh = rem >> 7;
        const int d   = rem & 127;
        const float p = prior[s];
        const float eta = fminf(fmaxf(1.0f + 0.5f * p, 0.5f), 2.0f);
        const float val = qkv[(size_t)s * 6144 + 5120 + kvh * 128 + d] * eta;
        Vt[((size_t)kvh * DH + d) * S_LEN + s] = f2bf(val);
    } else {
        const int j2 = idx - NQ - NV;
        if (j2 < 4 * S_LEN) {
            const int c = j2 >> 10;
            const int s = j2 & 1023;
            const float p = prior[s];
            const float bias = fminf(fmaxf(p, -5.0f), 5.0f);
            float v = 0.0f;
            if (c & 1) v += bias;
            if (c & 2) v += log1pf(0.5f * p);
            addvT[j2] = v * 1.4426950408889634f;
        }
    }
}

// Flash GQA attention v5: block-cooperative glds staging of K/V chunks,
// XOR-swizzled sK/sV, fixed-max exp2 softmax, waves own q-rows.
__global__ __launch_bounds__(256)
void attn5(const unsigned short* __restrict__ Qb, const unsigned short* __restrict__ Kb,
           const unsigned short* __restrict__ Vt, const float* __restrict__ addvT,
           const float* __restrict__ hm1, const float* __restrict__ hm2,
           unsigned short* __restrict__ ctx)
{
    __shared__ __attribute__((aligned(16))) unsigned short sK[32 * 128]; // [key][d] swz r&7
    __shared__ __attribute__((aligned(16))) unsigned short sV[128 * 32]; // [d][key] swz r&3
    __shared__ __attribute__((aligned(16))) short sP[4][16 * 40];

    const int h    = blockIdx.x;
    const int qb   = blockIdx.y;
    const int tid  = threadIdx.x;
    const int wave = tid >> 6;
    const int lane = tid & 63;
    const int l15  = lane & 15;
    const int quad = lane >> 4;
    const int q0   = qb * 64 + wave * 16;
    const int kvh  = h >> 2;
    const int combo = (hm1[h] > 0.5f ? 1 : 0) + (hm2[h] > 0.5f ? 2 : 0);
    const float* av = addvT + combo * S_LEN;

    const unsigned short* ksrcE = Kb + ((size_t)kvh * S_LEN + (lane >> 4)) * DH
                                  + (((lane & 15) ^ (lane >> 4)) * 8);
    const unsigned short* ksrcO = Kb + ((size_t)kvh * S_LEN + (lane >> 4)) * DH
                                  + (((lane & 15) ^ (4 + (lane >> 4))) * 8);
    const unsigned short* vsrc0 = Vt + ((size_t)kvh * DH + (lane >> 2)) * S_LEN
                                  + (((lane & 3) ^ ((lane >> 2) & 3)) * 8);

    sh8 qf[4];
    {
        const unsigned short* qbase = Qb + ((size_t)h * S_LEN + q0 + l15) * DH + quad * 8;
#pragma unroll
        for (int kc = 0; kc < 4; kc++)
            qf[kc] = *(const sh8*)(qbase + kc * 32);
    }

    f4 O[8];
#pragma unroll
    for (int dt = 0; dt < 8; dt++) O[dt] = f4{0.0f, 0.0f, 0.0f, 0.0f};
    float lrun[4] = {0.0f, 0.0f, 0.0f, 0.0f};

    short* pl = &sP[wave][0];
    const int sw = l15 & 7;
    const int sv = l15 & 3;
    const int nch = 2 * qb + 2;

    for (int c = 0; c < nch; c++) {
        const int k0 = c * 32;
        __syncthreads();
        if (wave < 2) {
#pragma unroll
            for (int j = 0; j < 4; j++) {
                const int i = wave * 4 + j;
                const unsigned short* src = (j & 1) ? ksrcO : ksrcE;
                gl_lds16(src + (size_t)(k0 + 4 * i) * DH, &sK[i * 512]);
            }
        } else {
#pragma unroll
            for (int j = 0; j < 4; j++) {
                const int i = (wave - 2) * 4 + j;
                gl_lds16(vsrc0 + (size_t)(16 * i) * S_LEN + k0, &sV[i * 512]);
            }
        }
        __syncthreads();

#pragma unroll
        for (int t = 0; t < 2; t++) {
            f4 a = f4{0.0f, 0.0f, 0.0f, 0.0f};
#pragma unroll
            for (int kc = 0; kc < 4; kc++) {
                const sh8 kfr = *(const sh8*)(&sK[(t * 16 + l15) * 128 + ((kc * 4 + quad) ^ sw) * 8]);
                a = __builtin_amdgcn_mfma_f32_16x16x32_bf16(qf[kc], kfr, a, 0, 0, 0);
            }
            const int key = k0 + t * 16 + l15;
            const float ad = av[key];
#pragma unroll
            for (int r = 0; r < 4; r++) {
                const int qrow = q0 + quad * 4 + r;
                float ex = exp2f(a[r] + ad);
                ex = (key <= qrow) ? ex : 0.0f;
                lrun[r] += ex;
                pl[(quad * 4 + r) * 40 + t * 16 + l15] = (short)f2bf(ex);
            }
        }
        asm volatile("s_waitcnt lgkmcnt(0)" ::: "memory");
        const sh8 ap = *(const sh8*)(&pl[l15 * 40 + quad * 8]);
#pragma unroll
        for (int dt = 0; dt < 8; dt++) {
            const sh8 vfr = *(const sh8*)(&sV[(dt * 16 + l15) * 32 + (quad ^ sv) * 8]);
            O[dt] = __builtin_amdgcn_mfma_f32_16x16x32_bf16(ap, vfr, O[dt], 0, 0, 0);
        }
    }

#pragma unroll
    for (int r = 0; r < 4; r++) {
        float l = lrun[r];
        l += __shfl_xor(l, 1); l += __shfl_xor(l, 2);
        l += __shfl_xor(l, 4); l += __shfl_xor(l, 8);
        const float inv = 1.0f / l;
        const int row = q0 + quad * 4 + r;
        unsigned short* cp = ctx + (size_t)row * HID_DIM + h * DH;
#pragma unroll
        for (int dt = 0; dt < 8; dt++)
            cp[dt * 16 + l15] = f2bf(O[dt][r] * inv);
    }
}

// ========================= FALLBACK (round-1, proven @54.5MB) ===============

#define LDSW 40

__global__ __launch_bounds__(256)
void gemm_bt(const float* __restrict__ A,
             const float* __restrict__ B0, const float* __restrict__ B1,
             const float* __restrict__ B2, int n_b1, int n_b2,
             float* __restrict__ C, int M, int N, int K, int ldc)
{
    __shared__ __attribute__((aligned(16))) short sA[128 * LDSW];
    __shared__ __attribute__((aligned(16))) short sB[128 * LDSW];
    const int tid  = threadIdx.x;
    const int m0   = blockIdx.y * 128;
    const int n0   = blockIdx.x * 128;
    const float* Bp = B0; int nloc = n0;
    if (n0 >= n_b2)      { Bp = B2; nloc = n0 - n_b2; }
    else if (n0 >= n_b1) { Bp = B1; nloc = n0 - n_b1; }
    const int wave = tid >> 6, lane = tid & 63;
    const int l15 = lane & 15, quad = lane >> 4;
    const int wm = (wave >> 1) * 64, wn = (wave & 1) * 64;
    const int rb = tid >> 3, c4 = (tid & 7) * 4;
    f4 acc[4][4];
#pragma unroll
    for (int i = 0; i < 4; i++)
#pragma unroll
        for (int j = 0; j < 4; j++) acc[i][j] = f4{0.0f, 0.0f, 0.0f, 0.0f};
    for (int k0 = 0; k0 < K; k0 += 32) {
        __syncthreads();
#pragma unroll
        for (int i = 0; i < 4; i++) {
            const int row = rb + 32 * i;
            const float4 va = *(const float4*)(A  + (size_t)(m0 + row) * K + k0 + c4);
            const float4 vb = *(const float4*)(Bp + (size_t)(nloc + row) * K + k0 + c4);
            sh4 sa, sb;
            sa.x = (short)f2bf(va.x); sa.y = (short)f2bf(va.y);
            sa.z = (short)f2bf(va.z); sa.w = (short)f2bf(va.w);
            sb.x = (short)f2bf(vb.x); sb.y = (short)f2bf(vb.y);
            sb.z = (short)f2bf(vb.z); sb.w = (short)f2bf(vb.w);
            *(sh4*)(&sA[row * LDSW + c4]) = sa;
            *(sh4*)(&sB[row * LDSW + c4]) = sb;
        }
        __syncthreads();
        sh8 af[4], bf[4];
#pragma unroll
        for (int i = 0; i < 4; i++) af[i] = *(const sh8*)(&sA[(wm + i * 16 + l15) * LDSW + quad * 8]);
#pragma unroll
        for (int j = 0; j < 4; j++) bf[j] = *(const sh8*)(&sB[(wn + j * 16 + l15) * LDSW + quad * 8]);
#pragma unroll
        for (int i = 0; i < 4; i++)
#pragma unroll
            for (int j = 0; j < 4; j++)
                acc[i][j] = __builtin_amdgcn_mfma_f32_16x16x32_bf16(af[i], bf[j], acc[i][j], 0, 0, 0);
    }
#pragma unroll
    for (int i = 0; i < 4; i++) {
        const int mrow = m0 + wm + i * 16 + quad * 4;
#pragma unroll
        for (int j = 0; j < 4; j++) {
            const int ncol = n0 + wn + j * 16 + l15;
#pragma unroll
            for (int r = 0; r < 4; r++)
                C[(size_t)(mrow + r) * ldc + ncol] = acc[i][j][r];
        }
    }
}

__global__ void prep_rope(const float* __restrict__ qkv, const int* __restrict__ pos_ids,
                          const float* __restrict__ prior,
                          unsigned short* __restrict__ Qb, unsigned short* __restrict__ Kb,
                          unsigned short* __restrict__ Vt)
{
    const int idx = blockIdx.x * blockDim.x + threadIdx.x;
    const int NQ = S_LEN * 40 * 64;
    if (idx < NQ) {
        const int s = idx / (40 * 64);
        const int rem = idx % (40 * 64);
        const int hh = rem >> 6, i = rem & 63;
        const float pos = (float)pos_ids[s];
        const float invf = exp2f(-13.287712379549449f * (i * 0.015625f));
        const float ph = pos * invf;
        const float c = cosf(ph), sn = sinf(ph);
        if (hh < NH) {
            const float* base = qkv + (size_t)s * 6144 + hh * 128;
            const float x1 = base[i], x2 = base[i + 64];
            const float sc = 0.08838834764831845f;
            unsigned short* q = Qb + ((size_t)hh * S_LEN + s) * DH;
            q[i] = f2bf((x1 * c - x2 * sn) * sc);
            q[i + 64] = f2bf((x2 * c + x1 * sn) * sc);
        } else {
            const int kvh = hh - NH;
            const float* base = qkv + (size_t)s * 6144 + 4096 + kvh * 128;
            const float p = prior[s];
            const float gamma = fminf(fmaxf(1.0f + 0.5f * p, 0.5f), 2.0f);
            const float x1 = base[i], x2 = base[i + 64];
            unsigned short* kp = Kb + ((size_t)kvh * S_LEN + s) * DH;
            kp[i] = f2bf((x1 * c - x2 * sn) * gamma);
            kp[i + 64] = f2bf((x2 * c + x1 * sn) * gamma);
        }
    } else {
        const int j = idx - NQ;
        if (j < S_LEN * NKV * DH) {
            const int s = j / (NKV * DH);
            const int rem = j % (NKV * DH);
            const int kvh = rem >> 7, d = rem & 127;
            const float p = prior[s];
            const float eta = fminf(fmaxf(1.0f + 0.5f * p, 0.5f), 2.0f);
            const float val = qkv[(size_t)s * 6144 + 5120 + kvh * 128 + d] * eta;
            Vt[((size_t)kvh * DH + d) * S_LEN + s] = f2bf(val);
        }
    }
}

__global__ __launch_bounds__(256)
void attn_kernel(const unsigned short* __restrict__ Qb, const unsigned short* __restrict__ Kb,
                 const unsigned short* __restrict__ Vt, const float* __restrict__ prior,
                 const float* __restrict__ hm1, const float* __restrict__ hm2,
                 float* __restrict__ ctx)
{
    __shared__ __attribute__((aligned(16))) short p_lds[4][16 * LDSW];
    const int h = blockIdx.x, qb = blockIdx.y;
    const int wave = threadIdx.x >> 6, lane = threadIdx.x & 63;
    const int l15 = lane & 15, quad = lane >> 4;
    const int q0 = qb * 64 + wave * 16;
    const int kvh = h >> 2;
    const float m1 = hm1[h], m2 = hm2[h];
    const float NEG = -3.0e38f;
    sh8 qf[4];
    {
        const unsigned short* qbase = Qb + ((size_t)h * S_LEN + q0 + l15) * DH + quad * 8;
#pragma unroll
        for (int kc = 0; kc < 4; kc++) qf[kc] = *(const sh8*)(qbase + kc * 32);
    }
    f4 O[8];
#pragma unroll
    for (int dt = 0; dt < 8; dt++) O[dt] = f4{0.0f, 0.0f, 0.0f, 0.0f};
    float mrun[4], lrun[4];
#pragma unroll
    for (int r = 0; r < 4; r++) { mrun[r] = NEG; lrun[r] = 0.0f; }
    short* pl = &p_lds[wave][0];
    const int qmax = q0 + 15;
    for (int key0 = 0; key0 <= qmax; key0 += 32) {
        float sc[2][4];
#pragma unroll
        for (int t = 0; t < 2; t++) {
            const int kt = key0 + t * 16;
            const unsigned short* kb = Kb + ((size_t)kvh * S_LEN + kt + l15) * DH + quad * 8;
            f4 a = f4{0.0f, 0.0f, 0.0f, 0.0f};
#pragma unroll
            for (int kc = 0; kc < 4; kc++) {
                const sh8 bfr = *(const sh8*)(kb + kc * 32);
                a = __builtin_amdgcn_mfma_f32_16x16x32_bf16(qf[kc], bfr, a, 0, 0, 0);
            }
            const int key = kt + l15;
            const float p = prior[key];
            const float bias = fminf(fmaxf(p, -5.0f), 5.0f);
            const float addv = m1 * bias + m2 * logf(1.0f + 0.5f * p);
#pragma unroll
            for (int r = 0; r < 4; r++) {
                const int qrow = q0 + quad * 4 + r;
                sc[t][r] = (key <= qrow) ? (a[r] + addv) : NEG;
            }
        }
        float cm[4], mnew[4], alpha[4], rs[4];
#pragma unroll
        for (int r = 0; r < 4; r++) {
            cm[r] = fmaxf(sc[0][r], sc[1][r]);
            cm[r] = fmaxf(cm[r], __shfl_xor(cm[r], 1));
            cm[r] = fmaxf(cm[r], __shfl_xor(cm[r], 2));
            cm[r] = fmaxf(cm[r], __shfl_xor(cm[r], 4));
            cm[r] = fmaxf(cm[r], __shfl_xor(cm[r], 8));
            mnew[r] = fmaxf(mrun[r], cm[r]);
            alpha[r] = expf(mrun[r] - mnew[r]);
        }
        float e[2][4];
#pragma unroll
        for (int t = 0; t < 2; t++)
#pragma unroll
            for (int r = 0; r < 4; r++) e[t][r] = expf(sc[t][r] - mnew[r]);
#pragma unroll
        for (int r = 0; r < 4; r++) {
            rs[r] = e[0][r] + e[1][r];
            rs[r] += __shfl_xor(rs[r], 1); rs[r] += __shfl_xor(rs[r], 2);
            rs[r] += __shfl_xor(rs[r], 4); rs[r] += __shfl_xor(rs[r], 8);
            lrun[r] = lrun[r] * alpha[r] + rs[r];
            mrun[r] = mnew[r];
        }
#pragma unroll
        for (int dt = 0; dt < 8; dt++)
#pragma unroll
            for (int r = 0; r < 4; r++) O[dt][r] *= alpha[r];
#pragma unroll
        for (int t = 0; t < 2; t++)
#pragma unroll
            for (int r = 0; r < 4; r++)
                pl[(quad * 4 + r) * LDSW + t * 16 + l15] = (short)f2bf(e[t][r]);
        asm volatile("s_waitcnt lgkmcnt(0)" ::: "memory");
        const sh8 ap = *(const sh8*)(&pl[l15 * LDSW + quad * 8]);
        const unsigned short* vb = Vt + ((size_t)kvh * DH + l15) * S_LEN + key0 + quad * 8;
#pragma unroll
        for (int dt = 0; dt < 8; dt++) {
            const sh8 bfv = *(const sh8*)(vb + (size_t)dt * 16 * S_LEN);
            O[dt] = __builtin_amdgcn_mfma_f32_16x16x32_bf16(ap, bfv, O[dt], 0, 0, 0);
        }
    }
#pragma unroll
    for (int r = 0; r < 4; r++) {
        const float inv = 1.0f / lrun[r];
        const int row = q0 + quad * 4 + r;
        float* cp = ctx + (size_t)row * HID_DIM + h * DH;
#pragma unroll
        for (int dt = 0; dt < 8; dt++) cp[dt * 16 + l15] = O[dt][r] * inv;
    }
}

// ============================================================================

extern "C" void kernel_launch(void* const* d_in, const int* in_sizes, int n_in,
                              void* d_out, int out_size, void* d_ws, size_t ws_size,
                              hipStream_t stream)
{
    const float* hidden  = (const float*)d_in[0];
    const int*   pos_ids = (const int*)d_in[2];
    const float* Wq = (const float*)d_in[3];
    const float* Wk = (const float*)d_in[4];
    const float* Wv = (const float*)d_in[5];
    const float* Wo = (const float*)d_in[6];
    const float* prior = (const float*)d_in[7];
    const float* hm1 = (const float*)d_in[8];
    const float* hm2 = (const float*)d_in[9];
    float* out = (float*)d_out;
    char* ws = (char*)d_ws;

    const size_t FAST_NEED = 96485376ull;
    if (ws_size >= FAST_NEED) {
        unsigned short* Wbuf = (unsigned short*)ws;                  // 50,331,648
        unsigned short* Cbf  = (unsigned short*)(ws + 33554432);     // ctx bf16, aliases Wbuf tail in phase 2
        unsigned short* Hbf  = (unsigned short*)(ws + 50331648);     //  8,388,608
        float*          qkv  = (float*)(ws + 58720256);              // 25,165,824
        unsigned short* Qb   = (unsigned short*)(ws + 83886080);     //  8,388,608
        unsigned short* Kb   = (unsigned short*)(ws + 92274688);     //  2,097,152
        unsigned short* Vt   = (unsigned short*)(ws + 94371840);     //  2,097,152
        float*          addv = (float*)(ws + 96468992);              //     16,384

        hipMemsetAsync(qkv, 0, 25165824, stream);
        hipMemsetAsync(out, 0, 16777216, stream);
        cvt_hw<<<28672, 256, 0, stream>>>(hidden, Wq, Wk, Wv, Hbf, Wbuf);
        gemm_db<<<dim3(48, 8, 2), 256, 0, stream>>>(Hbf, Wbuf, qkv, 4096, 2, 6144);
        prep2<<<14352, 256, 0, stream>>>(qkv, pos_ids, prior, Qb, Kb, Vt, addv);
        cvt_wo<<<16384, 256, 0, stream>>>(Wo, Wbuf);                 // reuse Wbuf[0:33.5MB]
        attn5<<<dim3(32, 16), 256, 0, stream>>>(Qb, Kb, Vt, addv, hm1, hm2, Cbf);
        gemm_db<<<dim3(32, 8, 2), 256, 0, stream>>>(Cbf, Wbuf, out, 4096, 2, 4096);
    } else {
        float*          qkv = (float*)ws;
        float*          ctx = (float*)(ws + 25165824);
        unsigned short* Qb  = (unsigned short*)(ws + 41943040);
        unsigned short* Kb  = (unsigned short*)(ws + 50331648);
        unsigned short* Vt  = (unsigned short*)(ws + 52428800);
        gemm_bt<<<dim3(48, 8), 256, 0, stream>>>(hidden, Wq, Wk, Wv, 4096, 5120,
                                                 qkv, 1024, 6144, 4096, 6144);
        prep_rope<<<14336, 256, 0, stream>>>(qkv, pos_ids, prior, Qb, Kb, Vt);
        attn_kernel<<<dim3(32, 16), 256, 0, stream>>>(Qb, Kb, Vt, prior, hm1, hm2, ctx);
        gemm_bt<<<dim3(32, 8), 256, 0, stream>>>(ctx, Wo, Wo, Wo, 1 << 30, 1 << 30,
                                                 out, 1024, 4096, 4096, 4096);
    }
}

// Round 8
// 409.818 us; speedup vs baseline: 1.1585x; 1.0510x over previous
//
#include <hip/hip_runtime.h>
#include <math.h>

#define S_LEN 1024
#define HID_DIM 4096
#define NH 32
#define NKV 8
#define DH 128

typedef __attribute__((ext_vector_type(8))) short sh8;
typedef __attribute__((ext_vector_type(4))) short sh4;
typedef __attribute__((ext_vector_type(4))) float f4;

__device__ __forceinline__ unsigned short f2bf(float x) {
    union { float f; unsigned int u; } v; v.f = x;
    unsigned int r = v.u + 0x7FFFu + ((v.u >> 16) & 1u);
    return (unsigned short)(r >> 16);
}

__device__ __forceinline__ void gl_lds16(const unsigned short* g, unsigned short* l) {
    __builtin_amdgcn_global_load_lds(
        (const __attribute__((address_space(1))) unsigned int*)g,
        (__attribute__((address_space(3))) unsigned int*)l, 16, 0, 0);
}

// ============================ FAST PATH =====================================

__global__ void cvt_hw(const float* __restrict__ hidden, const float* __restrict__ Wq,
                       const float* __restrict__ Wk, const float* __restrict__ Wv,
                       unsigned short* __restrict__ hbf, unsigned short* __restrict__ wbuf)
{
    const int idx = blockIdx.x * 256 + threadIdx.x;
    const int NH4 = (S_LEN * HID_DIM) / 4;
    float4 v;
    sh4* dst;
    if (idx < NH4) {
        v = ((const float4*)hidden)[idx];
        dst = (sh4*)hbf + idx;
    } else {
        const int j = idx - NH4;
        const int row = j >> 10;
        if (row < 4096)      v = ((const float4*)Wq)[j];
        else if (row < 5120) v = ((const float4*)Wk)[j - 4096 * 1024];
        else                 v = ((const float4*)Wv)[j - 5120 * 1024];
        dst = (sh4*)wbuf + j;
    }
    sh4 o;
    o.x = (short)f2bf(v.x); o.y = (short)f2bf(v.y);
    o.z = (short)f2bf(v.z); o.w = (short)f2bf(v.w);
    *dst = o;
}

__global__ void cvt_wo(const float* __restrict__ Wo, unsigned short* __restrict__ wbuf)
{
    const int idx = blockIdx.x * 256 + threadIdx.x;
    const float4 v = ((const float4*)Wo)[idx];
    sh4 o;
    o.x = (short)f2bf(v.x); o.y = (short)f2bf(v.y);
    o.z = (short)f2bf(v.z); o.w = (short)f2bf(v.w);
    ((sh4*)wbuf)[idx] = o;
}

// bf16 GEMM v5: 64x128 tile, BK=32, NO split-K (plain fp32 stores, zero
// atomics), pair-interleaved XOR swizzle (0 conflicts, r6-verified),
// single-barrier double-buffered K-loop (r7-verified). M-split supplies
// parallelism: QKV 48x16=768 blocks, Wo 32x16=512 blocks. LDS 20KB/block.
__global__ __launch_bounds__(256)
void gemm_t(const unsigned short* __restrict__ A, const unsigned short* __restrict__ B,
            float* __restrict__ C, int K, int ldc)
{
    __shared__ __attribute__((aligned(16))) unsigned short sA[2][64 * 32];
    __shared__ __attribute__((aligned(16))) unsigned short sB[2][128 * 32];

    const int tid  = threadIdx.x;
    const int wave = tid >> 6;
    const int lane = tid & 63;
    const int l15  = lane & 15;
    const int quad = lane >> 4;
    const int m0   = blockIdx.y * 64;
    const int n0   = blockIdx.x * 128;
    const int wm   = (wave >> 1) * 32;   // wave row offset (2x2 wave grid)
    const int wn   = (wave & 1) * 64;    // wave col offset

    // staging lane map within a 16-row chunk (r6 scheme): pair l>>3, phys slot
    // l&7, logical slot s=(l&7)^((l>>3)&7) -> src row 2*(l>>3)+(s>>2),
    // src 16B-chunk s&3.
    const int sslot = (lane & 7) ^ ((lane >> 3) & 7);
    const int srow  = 2 * (lane >> 3) + (sslot >> 2);
    const int scol  = (sslot & 3) * 8;

    // wave w stages: A chunk w (rows 16w..16w+16), B chunks w and w+4.
    const unsigned short* Ag  = A + (size_t)(m0 + 16 * wave + srow) * K + scol;
    const unsigned short* Bg1 = B + (size_t)(n0 + 16 * wave + srow) * K + scol;
    const unsigned short* Bg2 = B + (size_t)(n0 + 64 + 16 * wave + srow) * K + scol;

    f4 acc[2][4];
#pragma unroll
    for (int i = 0; i < 2; i++)
#pragma unroll
        for (int j = 0; j < 4; j++)
            acc[i][j] = f4{0.0f, 0.0f, 0.0f, 0.0f};

    // read-side phys chunk for logical chunk 'quad' in row (base16*i + l15)
    const int rphys = ((((l15 & 1) << 2) + quad) ^ (l15 >> 1)) * 8;

    // prologue: stage buffer 0
    gl_lds16(Ag,  &sA[0][wave * 512]);
    gl_lds16(Bg1, &sB[0][wave * 512]);
    gl_lds16(Bg2, &sB[0][2048 + wave * 512]);

    for (int k0 = 0; k0 < K; k0 += 32) {
        const int cur = (k0 >> 5) & 1;
        __syncthreads();                       // 'cur' staging landed
        const int k1 = k0 + 32;
        if (k1 < K) {                          // prefetch next into cur^1
            gl_lds16(Ag + k1,  &sA[cur ^ 1][wave * 512]);
            gl_lds16(Bg1 + k1, &sB[cur ^ 1][wave * 512]);
            gl_lds16(Bg2 + k1, &sB[cur ^ 1][2048 + wave * 512]);
        }

        sh8 af[2], bf[4];
#pragma unroll
        for (int i = 0; i < 2; i++)
            af[i] = *(const sh8*)(&sA[cur][((wm + i * 16 + l15) >> 1) * 64 + rphys]);
#pragma unroll
        for (int j = 0; j < 4; j++)
            bf[j] = *(const sh8*)(&sB[cur][((wn + j * 16 + l15) >> 1) * 64 + rphys]);
#pragma unroll
        for (int i = 0; i < 2; i++)
#pragma unroll
            for (int j = 0; j < 4; j++)
                acc[i][j] = __builtin_amdgcn_mfma_f32_16x16x32_bf16(af[i], bf[j], acc[i][j], 0, 0, 0);
    }

#pragma unroll
    for (int i = 0; i < 2; i++) {
        const int mrow = m0 + wm + i * 16 + quad * 4;
#pragma unroll
        for (int j = 0; j < 4; j++) {
            const int ncol = n0 + wn + j * 16 + l15;
#pragma unroll
            for (int r = 0; r < 4; r++)
                C[(size_t)(mrow + r) * ldc + ncol] = acc[i][j][r];
        }
    }
}

__global__ void prep2(const float* __restrict__ qkv, const int* __restrict__ pos_ids,
                      const float* __restrict__ prior,
                      unsigned short* __restrict__ Qb, unsigned short* __restrict__ Kb,
                      unsigned short* __restrict__ Vt, float* __restrict__ addvT)
{
    const int idx = blockIdx.x * blockDim.x + threadIdx.x;
    const int NQ = S_LEN * 40 * 64;
    const int NV = S_LEN * NKV * DH;
    if (idx < NQ) {
        const int s   = idx / (40 * 64);
        const int rem = idx % (40 * 64);
        const int hh  = rem >> 6;
        const int i   = rem & 63;
        const float pos  = (float)pos_ids[s];
        const float invf = exp2f(-13.287712379549449f * (i * 0.015625f));
        const float ph = pos * invf;
        const float c = cosf(ph), sn = sinf(ph);
        if (hh < NH) {
            const float* base = qkv + (size_t)s * 6144 + hh * 128;
            const float x1 = base[i], x2 = base[i + 64];
            const float sc = 0.08838834764831845f * 1.4426950408889634f; // log2e/sqrt(128)
            unsigned short* q = Qb + ((size_t)hh * S_LEN + s) * DH;
            q[i]      = f2bf((x1 * c - x2 * sn) * sc);
            q[i + 64] = f2bf((x2 * c + x1 * sn) * sc);
        } else {
            const int kvh = hh - NH;
            const float* base = qkv + (size_t)s * 6144 + 4096 + kvh * 128;
            const float p = prior[s];
            const float gamma = fminf(fmaxf(1.0f + 0.5f * p, 0.5f), 2.0f);
            const float x1 = base[i], x2 = base[i + 64];
            unsigned short* kp = Kb + ((size_t)kvh * S_LEN + s) * DH;
            kp[i]      = f2bf((x1 * c - x2 * sn) * gamma);
            kp[i + 64] = f2bf((x2 * c + x1 * sn) * gamma);
        }
    } else if (idx < NQ + NV) {
        const int j = idx - NQ;
        const int s   = j / (NKV * DH);
        const int rem = j % (NKV * DH);
        const int kvh = rem >> 7;
        const int d   = rem & 127;
        const float p = prior[s];
        const float eta = fminf(fmaxf(1.0f + 0.5f * p, 0.5f), 2.0f);
        const float val = qkv[(size_t)s * 6144 + 5120 + kvh * 128 + d] * eta;
        Vt[((size_t)kvh * DH + d) * S_LEN + s] = f2bf(val);
    } else {
        const int j2 = idx - NQ - NV;
        if (j2 < 4 * S_LEN) {
            const int c = j2 >> 10;
            const int s = j2 & 1023;
            const float p = prior[s];
            const float bias = fminf(fmaxf(p, -5.0f), 5.0f);
            float v = 0.0f;
            if (c & 1) v += bias;
            if (c & 2) v += log1pf(0.5f * p);
            addvT[j2] = v * 1.4426950408889634f;
        }
    }
}

// Flash GQA attention v5: block-cooperative glds staging of K/V chunks,
// XOR-swizzled sK/sV, fixed-max exp2 softmax, waves own q-rows.
// qb reversed so the longest (most-chunk) blocks dispatch first.
__global__ __launch_bounds__(256)
void attn5(const unsigned short* __restrict__ Qb, const unsigned short* __restrict__ Kb,
           const unsigned short* __restrict__ Vt, const float* __restrict__ addvT,
           const float* __restrict__ hm1, const float* __restrict__ hm2,
           unsigned short* __restrict__ ctx)
{
    __shared__ __attribute__((aligned(16))) unsigned short sK[32 * 128]; // [key][d] swz r&7
    __shared__ __attribute__((aligned(16))) unsigned short sV[128 * 32]; // [d][key] swz r&3
    __shared__ __attribute__((aligned(16))) short sP[4][16 * 40];

    const int h    = blockIdx.x;
    const int qb   = (gridDim.y - 1) - blockIdx.y;   // longest blocks first
    const int tid  = threadIdx.x;
    const int wave = tid >> 6;
    const int lane = tid & 63;
    const int l15  = lane & 15;
    const int quad = lane >> 4;
    const int q0   = qb * 64 + wave * 16;
    const int kvh  = h >> 2;
    const int combo = (hm1[h] > 0.5f ? 1 : 0) + (hm2[h] > 0.5f ? 2 : 0);
    const float* av = addvT + combo * S_LEN;

    const unsigned short* ksrcE = Kb + ((size_t)kvh * S_LEN + (lane >> 4)) * DH
                                  + (((lane & 15) ^ (lane >> 4)) * 8);
    const unsigned short* ksrcO = Kb + ((size_t)kvh * S_LEN + (lane >> 4)) * DH
                                  + (((lane & 15) ^ (4 + (lane >> 4))) * 8);
    const unsigned short* vsrc0 = Vt + ((size_t)kvh * DH + (lane >> 2)) * S_LEN
                                  + (((lane & 3) ^ ((lane >> 2) & 3)) * 8);

    sh8 qf[4];
    {
        const unsigned short* qbase = Qb + ((size_t)h * S_LEN + q0 + l15) * DH + quad * 8;
#pragma unroll
        for (int kc = 0; kc < 4; kc++)
            qf[kc] = *(const sh8*)(qbase + kc * 32);
    }

    f4 O[8];
#pragma unroll
    for (int dt = 0; dt < 8; dt++) O[dt] = f4{0.0f, 0.0f, 0.0f, 0.0f};
    float lrun[4] = {0.0f, 0.0f, 0.0f, 0.0f};

    short* pl = &sP[wave][0];
    const int sw = l15 & 7;
    const int sv = l15 & 3;
    const int nch = 2 * qb + 2;

    for (int c = 0; c < nch; c++) {
        const int k0 = c * 32;
        __syncthreads();
        if (wave < 2) {
#pragma unroll
            for (int j = 0; j < 4; j++) {
                const int i = wave * 4 + j;
                const unsigned short* src = (j & 1) ? ksrcO : ksrcE;
                gl_lds16(src + (size_t)(k0 + 4 * i) * DH, &sK[i * 512]);
            }
        } else {
#pragma unroll
            for (int j = 0; j < 4; j++) {
                const int i = (wave - 2) * 4 + j;
                gl_lds16(vsrc0 + (size_t)(16 * i) * S_LEN + k0, &sV[i * 512]);
            }
        }
        __syncthreads();

#pragma unroll
        for (int t = 0; t < 2; t++) {
            f4 a = f4{0.0f, 0.0f, 0.0f, 0.0f};
#pragma unroll
            for (int kc = 0; kc < 4; kc++) {
                const sh8 kfr = *(const sh8*)(&sK[(t * 16 + l15) * 128 + ((kc * 4 + quad) ^ sw) * 8]);
                a = __builtin_amdgcn_mfma_f32_16x16x32_bf16(qf[kc], kfr, a, 0, 0, 0);
            }
            const int key = k0 + t * 16 + l15;
            const float ad = av[key];
#pragma unroll
            for (int r = 0; r < 4; r++) {
                const int qrow = q0 + quad * 4 + r;
                float ex = exp2f(a[r] + ad);
                ex = (key <= qrow) ? ex : 0.0f;
                lrun[r] += ex;
                pl[(quad * 4 + r) * 40 + t * 16 + l15] = (short)f2bf(ex);
            }
        }
        asm volatile("s_waitcnt lgkmcnt(0)" ::: "memory");
        const sh8 ap = *(const sh8*)(&pl[l15 * 40 + quad * 8]);
#pragma unroll
        for (int dt = 0; dt < 8; dt++) {
            const sh8 vfr = *(const sh8*)(&sV[(dt * 16 + l15) * 32 + (quad ^ sv) * 8]);
            O[dt] = __builtin_amdgcn_mfma_f32_16x16x32_bf16(ap, vfr, O[dt], 0, 0, 0);
        }
    }

#pragma unroll
    for (int r = 0; r < 4; r++) {
        float l = lrun[r];
        l += __shfl_xor(l, 1); l += __shfl_xor(l, 2);
        l += __shfl_xor(l, 4); l += __shfl_xor(l, 8);
        const float inv = 1.0f / l;
        const int row = q0 + quad * 4 + r;
        unsigned short* cp = ctx + (size_t)row * HID_DIM + h * DH;
#pragma unroll
        for (int dt = 0; dt < 8; dt++)
            cp[dt * 16 + l15] = f2bf(O[dt][r] * inv);
    }
}

// ========================= FALLBACK (round-1, proven @54.5MB) ===============

#define LDSW 40

__global__ __launch_bounds__(256)
void gemm_bt(const float* __restrict__ A,
             const float* __restrict__ B0, const float* __restrict__ B1,
             const float* __restrict__ B2, int n_b1, int n_b2,
             float* __restrict__ C, int M, int N, int K, int ldc)
{
    __shared__ __attribute__((aligned(16))) short sA[128 * LDSW];
    __shared__ __attribute__((aligned(16))) short sB[128 * LDSW];
    const int tid  = threadIdx.x;
    const int m0   = blockIdx.y * 128;
    const int n0   = blockIdx.x * 128;
    const float* Bp = B0; int nloc = n0;
    if (n0 >= n_b2)      { Bp = B2; nloc = n0 - n_b2; }
    else if (n0 >= n_b1) { Bp = B1; nloc = n0 - n_b1; }
    const int wave = tid >> 6, lane = tid & 63;
    const int l15 = lane & 15, quad = lane >> 4;
    const int wm = (wave >> 1) * 64, wn = (wave & 1) * 64;
    const int rb = tid >> 3, c4 = (tid & 7) * 4;
    f4 acc[4][4];
#pragma unroll
    for (int i = 0; i < 4; i++)
#pragma unroll
        for (int j = 0; j < 4; j++) acc[i][j] = f4{0.0f, 0.0f, 0.0f, 0.0f};
    for (int k0 = 0; k0 < K; k0 += 32) {
        __syncthreads();
#pragma unroll
        for (int i = 0; i < 4; i++) {
            const int row = rb + 32 * i;
            const float4 va = *(const float4*)(A  + (size_t)(m0 + row) * K + k0 + c4);
            const float4 vb = *(const float4*)(Bp + (size_t)(nloc + row) * K + k0 + c4);
            sh4 sa, sb;
            sa.x = (short)f2bf(va.x); sa.y = (short)f2bf(va.y);
            sa.z = (short)f2bf(va.z); sa.w = (short)f2bf(va.w);
            sb.x = (short)f2bf(vb.x); sb.y = (short)f2bf(vb.y);
            sb.z = (short)f2bf(vb.z); sb.w = (short)f2bf(vb.w);
            *(sh4*)(&sA[row * LDSW + c4]) = sa;
            *(sh4*)(&sB[row * LDSW + c4]) = sb;
        }
        __syncthreads();
        sh8 af[4], bf[4];
#pragma unroll
        for (int i = 0; i < 4; i++) af[i] = *(const sh8*)(&sA[(wm + i * 16 + l15) * LDSW + quad * 8]);
#pragma unroll
        for (int j = 0; j < 4; j++) bf[j] = *(const sh8*)(&sB[(wn + j * 16 + l15) * LDSW + quad * 8]);
#pragma unroll
        for (int i = 0; i < 4; i++)
#pragma unroll
            for (int j = 0; j < 4; j++)
                acc[i][j] = __builtin_amdgcn_mfma_f32_16x16x32_bf16(af[i], bf[j], acc[i][j], 0, 0, 0);
    }
#pragma unroll
    for (int i = 0; i < 4; i++) {
        const int mrow = m0 + wm + i * 16 + quad * 4;
#pragma unroll
        for (int j = 0; j < 4; j++) {
            const int ncol = n0 + wn + j * 16 + l15;
#pragma unroll
            for (int r = 0; r < 4; r++)
                C[(size_t)(mrow + r) * ldc + ncol] = acc[i][j][r];
        }
    }
}

__global__ void prep_rope(const float* __restrict__ qkv, const int* __restrict__ pos_ids,
                          const float* __restrict__ prior,
                          unsigned short* __restrict__ Qb, unsigned short* __restrict__ Kb,
                          unsigned short* __restrict__ Vt)
{
    const int idx = blockIdx.x * blockDim.x + threadIdx.x;
    const int NQ = S_LEN * 40 * 64;
    if (idx < NQ) {
        const int s = idx / (40 * 64);
        const int rem = idx % (40 * 64);
        const int hh = rem >> 6, i = rem & 63;
        const float pos = (float)pos_ids[s];
        const float invf = exp2f(-13.287712379549449f * (i * 0.015625f));
        const float ph = pos * invf;
        const float c = cosf(ph), sn = sinf(ph);
        if (hh < NH) {
            const float* base = qkv + (size_t)s * 6144 + hh * 128;
            const float x1 = base[i], x2 = base[i + 64];
            const float sc = 0.08838834764831845f;
            unsigned short* q = Qb + ((size_t)hh * S_LEN + s) * DH;
            q[i] = f2bf((x1 * c - x2 * sn) * sc);
            q[i + 64] = f2bf((x2 * c + x1 * sn) * sc);
        } else {
            const int kvh = hh - NH;
            const float* base = qkv + (size_t)s * 6144 + 4096 + kvh * 128;
            const float p = prior[s];
            const float gamma = fminf(fmaxf(1.0f + 0.5f * p, 0.5f), 2.0f);
            const float x1 = base[i], x2 = base[i + 64];
            unsigned short* kp = Kb + ((size_t)kvh * S_LEN + s) * DH;
            kp[i] = f2bf((x1 * c - x2 * sn) * gamma);
            kp[i + 64] = f2bf((x2 * c + x1 * sn) * gamma);
        }
    } else {
        const int j = idx - NQ;
        if (j < S_LEN * NKV * DH) {
            const int s = j / (NKV * DH);
            const int rem = j % (NKV * DH);
            const int kvh = rem >> 7, d = rem & 127;
            const float p = prior[s];
            const float eta = fminf(fmaxf(1.0f + 0.5f * p, 0.5f), 2.0f);
            const float val = qkv[(size_t)s * 6144 + 5120 + kvh * 128 + d] * eta;
            Vt[((size_t)kvh * DH + d) * S_LEN + s] = f2bf(val);
        }
    }
}

__global__ __launch_bounds__(256)
void attn_kernel(const unsigned short* __restrict__ Qb, const unsigned short* __restrict__ Kb,
                 const unsigned short* __restrict__ Vt, const float* __restrict__ prior,
                 const float* __restrict__ hm1, const float* __restrict__ hm2,
                 float* __restrict__ ctx)
{
    __shared__ __attribute__((aligned(16))) short p_lds[4][16 * LDSW];
    const int h = blockIdx.x, qb = blockIdx.y;
    const int wave = threadIdx.x >> 6, lane = threadIdx.x & 63;
    const int l15 = lane & 15, quad = lane >> 4;
    const int q0 = qb * 64 + wave * 16;
    const int kvh = h >> 2;
    const float m1 = hm1[h], m2 = hm2[h];
    const float NEG = -3.0e38f;
    sh8 qf[4];
    {
        const unsigned short* qbase = Qb + ((size_t)h * S_LEN + q0 + l15) * DH + quad * 8;
#pragma unroll
        for (int kc = 0; kc < 4; kc++) qf[kc] = *(const sh8*)(qbase + kc * 32);
    }
    f4 O[8];
#pragma unroll
    for (int dt = 0; dt < 8; dt++) O[dt] = f4{0.0f, 0.0f, 0.0f, 0.0f};
    float mrun[4], lrun[4];
#pragma unroll
    for (int r = 0; r < 4; r++) { mrun[r] = NEG; lrun[r] = 0.0f; }
    short* pl = &p_lds[wave][0];
    const int qmax = q0 + 15;
    for (int key0 = 0; key0 <= qmax; key0 += 32) {
        float sc[2][4];
#pragma unroll
        for (int t = 0; t < 2; t++) {
            const int kt = key0 + t * 16;
            const unsigned short* kb = Kb + ((size_t)kvh * S_LEN + kt + l15) * DH + quad * 8;
            f4 a = f4{0.0f, 0.0f, 0.0f, 0.0f};
#pragma unroll
            for (int kc = 0; kc < 4; kc++) {
                const sh8 bfr = *(const sh8*)(kb + kc * 32);
                a = __builtin_amdgcn_mfma_f32_16x16x32_bf16(qf[kc], bfr, a, 0, 0, 0);
            }
            const int key = kt + l15;
            const float p = prior[key];
            const float bias = fminf(fmaxf(p, -5.0f), 5.0f);
            const float addv = m1 * bias + m2 * logf(1.0f + 0.5f * p);
#pragma unroll
            for (int r = 0; r < 4; r++) {
                const int qrow = q0 + quad * 4 + r;
                sc[t][r] = (key <= qrow) ? (a[r] + addv) : NEG;
            }
        }
        float cm[4], mnew[4], alpha[4], rs[4];
#pragma unroll
        for (int r = 0; r < 4; r++) {
            cm[r] = fmaxf(sc[0][r], sc[1][r]);
            cm[r] = fmaxf(cm[r], __shfl_xor(cm[r], 1));
            cm[r] = fmaxf(cm[r], __shfl_xor(cm[r], 2));
            cm[r] = fmaxf(cm[r], __shfl_xor(cm[r], 4));
            cm[r] = fmaxf(cm[r], __shfl_xor(cm[r], 8));
            mnew[r] = fmaxf(mrun[r], cm[r]);
            alpha[r] = expf(mrun[r] - mnew[r]);
        }
        float e[2][4];
#pragma unroll
        for (int t = 0; t < 2; t++)
#pragma unroll
            for (int r = 0; r < 4; r++) e[t][r] = expf(sc[t][r] - mnew[r]);
#pragma unroll
        for (int r = 0; r < 4; r++) {
            rs[r] = e[0][r] + e[1][r];
            rs[r] += __shfl_xor(rs[r], 1); rs[r] += __shfl_xor(rs[r], 2);
            rs[r] += __shfl_xor(rs[r], 4); rs[r] += __shfl_xor(rs[r], 8);
            lrun[r] = lrun[r] * alpha[r] + rs[r];
            mrun[r] = mnew[r];
        }
#pragma unroll
        for (int dt = 0; dt < 8; dt++)
#pragma unroll
            for (int r = 0; r < 4; r++) O[dt][r] *= alpha[r];
#pragma unroll
        for (int t = 0; t < 2; t++)
#pragma unroll
            for (int r = 0; r < 4; r++)
                pl[(quad * 4 + r) * LDSW + t * 16 + l15] = (short)f2bf(e[t][r]);
        asm volatile("s_waitcnt lgkmcnt(0)" ::: "memory");
        const sh8 ap = *(const sh8*)(&pl[l15 * LDSW + quad * 8]);
        const unsigned short* vb = Vt + ((size_t)kvh * DH + l15) * S_LEN + key0 + quad * 8;
#pragma unroll
        for (int dt = 0; dt < 8; dt++) {
            const sh8 bfv = *(const sh8*)(vb + (size_t)dt * 16 * S_LEN);
            O[dt] = __builtin_amdgcn_mfma_f32_16x16x32_bf16(ap, bfv, O[dt], 0, 0, 0);
        }
    }
#pragma unroll
    for (int r = 0; r < 4; r++) {
        const float inv = 1.0f / lrun[r];
        const int row = q0 + quad * 4 + r;
        float* cp = ctx + (size_t)row * HID_DIM + h * DH;
#pragma unroll
        for (int dt = 0; dt < 8; dt++) cp[dt * 16 + l15] = O[dt][r] * inv;
    }
}

// ============================================================================

extern "C" void kernel_launch(void* const* d_in, const int* in_sizes, int n_in,
                              void* d_out, int out_size, void* d_ws, size_t ws_size,
                              hipStream_t stream)
{
    const float* hidden  = (const float*)d_in[0];
    const int*   pos_ids = (const int*)d_in[2];
    const float* Wq = (const float*)d_in[3];
    const float* Wk = (const float*)d_in[4];
    const float* Wv = (const float*)d_in[5];
    const float* Wo = (const float*)d_in[6];
    const float* prior = (const float*)d_in[7];
    const float* hm1 = (const float*)d_in[8];
    const float* hm2 = (const float*)d_in[9];
    float* out = (float*)d_out;
    char* ws = (char*)d_ws;

    const size_t FAST_NEED = 96485376ull;
    if (ws_size >= FAST_NEED) {
        unsigned short* Wbuf = (unsigned short*)ws;                  // 50,331,648
        unsigned short* Cbf  = (unsigned short*)(ws + 33554432);     // ctx bf16, aliases Wbuf tail in phase 2
        unsigned short* Hbf  = (unsigned short*)(ws + 50331648);     //  8,388,608
        float*          qkv  = (float*)(ws + 58720256);              // 25,165,824
        unsigned short* Qb   = (unsigned short*)(ws + 83886080);     //  8,388,608
        unsigned short* Kb   = (unsigned short*)(ws + 92274688);     //  2,097,152
        unsigned short* Vt   = (unsigned short*)(ws + 94371840);     //  2,097,152
        float*          addv = (float*)(ws + 96468992);              //     16,384

        cvt_hw<<<28672, 256, 0, stream>>>(hidden, Wq, Wk, Wv, Hbf, Wbuf);
        gemm_t<<<dim3(48, 16), 256, 0, stream>>>(Hbf, Wbuf, qkv, 4096, 6144);
        prep2<<<14352, 256, 0, stream>>>(qkv, pos_ids, prior, Qb, Kb, Vt, addv);
        cvt_wo<<<16384, 256, 0, stream>>>(Wo, Wbuf);                 // reuse Wbuf[0:33.5MB]
        attn5<<<dim3(32, 16), 256, 0, stream>>>(Qb, Kb, Vt, addv, hm1, hm2, Cbf);
        gemm_t<<<dim3(32, 16), 256, 0, stream>>>(Cbf, Wbuf, out, 4096, 4096);
    } else {
        float*          qkv = (float*)ws;
        float*          ctx = (float*)(ws + 25165824);
        unsigned short* Qb  = (unsigned short*)(ws + 41943040);
        unsigned short* Kb  = (unsigned short*)(ws + 50331648);
        unsigned short* Vt  = (unsigned short*)(ws + 52428800);
        gemm_bt<<<dim3(48, 8), 256, 0, stream>>>(hidden, Wq, Wk, Wv, 4096, 5120,
                                                 qkv, 1024, 6144, 4096, 6144);
        prep_rope<<<14336, 256, 0, stream>>>(qkv, pos_ids, prior, Qb, Kb, Vt);
        attn_kernel<<<dim3(32, 16), 256, 0, stream>>>(Qb, Kb, Vt, prior, hm1, hm2, ctx);
        gemm_bt<<<dim3(32, 8), 256, 0, stream>>>(ctx, Wo, Wo, Wo, 1 << 30, 1 << 30,
                                                 out, 1024, 4096, 4096, 4096);
    }
}